// Round 22
// baseline (56.931 us; speedup 1.0000x reference)
//
#include <hip/hip_runtime.h>
#include <hip/hip_bf16.h>
#include <hip/hip_fp8.h>

#define B_ROWS 8192
#define E_DIM  1024
#define MARGIN 0.2f
#define BK 64                 // fp8 elements per K-step (2 ktiles of 32)
#define NSTEPS (E_DIM / BK)   // 16
#define WSCALE 16.0f

typedef float f32x4 __attribute__((ext_vector_type(4)));

__device__ __forceinline__ void gload_lds16(const void* g, void* l) {
    __builtin_amdgcn_global_load_lds(
        (__attribute__((address_space(1))) void*)(g),
        (__attribute__((address_space(3))) void*)(l),
        16, 0, 0);
}

#define GATE(N) do { asm volatile("s_waitcnt vmcnt(" #N ")" ::: "memory"); \
                     __builtin_amdgcn_sched_barrier(0); } while (0)
#define RBAR()  do { __builtin_amdgcn_s_barrier(); \
                     __builtin_amdgcn_sched_barrier(0); } while (0)
#define LGKM0() do { asm volatile("s_waitcnt lgkmcnt(0)" ::: "memory"); \
                     __builtin_amdgcn_sched_barrier(0); } while (0)

__device__ __forceinline__ unsigned char to_fp8(float x) {
    return __hip_fp8_e4m3(x).__x;
}

// Fragment-packed layouts (unit = [panel64][ktile32], 2 KiB each):
//   unit byte (mi*512 + lane*8 + j) = value[row = panel*64 + mi*16 + (lane&15)]
//                                          [k   = ktile*32 + (lane>>4)*8 + j]
// blocks [0,4096): c-pack; [4096,4608): W-pack; [4608,4640): zero delta.
__global__ __launch_bounds__(256)
void prep_combo(const float* __restrict__ m, const float* __restrict__ trm,
                unsigned char* __restrict__ c8p,
                const float* __restrict__ W, unsigned char* __restrict__ wtp,
                float* __restrict__ delta) {
    const int tid = threadIdx.x;
    const int mi  = tid >> 6;
    const int l   = tid & 63;
    const int lr  = l & 15;
    const int hi  = l >> 4;
    if (blockIdx.x < 4096) {
        const int unit  = blockIdx.x;
        const int panel = unit >> 5;
        const int kt    = unit & 31;
        const size_t g  = (size_t)(panel * 64 + mi * 16 + lr) * E_DIM + kt * 32 + hi * 8;
        float4 m0 = *(const float4*)(m + g);
        float4 m1 = *(const float4*)(m + g + 4);
        float4 t0 = *(const float4*)(trm + g);
        float4 t1 = *(const float4*)(trm + g + 4);
        union { unsigned char b[8]; unsigned long long u; } r;
        r.b[0] = to_fp8(0.4f*m0.x + 0.6f*t0.x);
        r.b[1] = to_fp8(0.4f*m0.y + 0.6f*t0.y);
        r.b[2] = to_fp8(0.4f*m0.z + 0.6f*t0.z);
        r.b[3] = to_fp8(0.4f*m0.w + 0.6f*t0.w);
        r.b[4] = to_fp8(0.4f*m1.x + 0.6f*t1.x);
        r.b[5] = to_fp8(0.4f*m1.y + 0.6f*t1.y);
        r.b[6] = to_fp8(0.4f*m1.z + 0.6f*t1.z);
        r.b[7] = to_fp8(0.4f*m1.w + 0.6f*t1.w);
        *(unsigned long long*)(c8p + (size_t)unit * 2048 + mi * 512 + l * 8) = r.u;
    } else if (blockIdx.x < 4608) {
        const int unit = blockIdx.x - 4096;
        const int np   = unit >> 5;
        const int kt   = unit & 31;
        const int n    = np * 64 + mi * 16 + lr;
        const int k0   = kt * 32 + hi * 8;
        union { unsigned char b[8]; unsigned long long u; } r;
#pragma unroll
        for (int j = 0; j < 8; ++j)
            r.b[j] = to_fp8(W[(size_t)(k0 + j) * E_DIM + n] * WSCALE);
        *(unsigned long long*)(wtp + (size_t)unit * 2048 + mi * 512 + l * 8) = r.u;
    } else {
        delta[(blockIdx.x - 4608) * 256 + threadIdx.x] = 0.f;
    }
}

// PERSISTENT 2-JOB GEMM: grid 512, each block runs TWO 128x64 tile-jobs
// (1024 jobs total) with ONE continuously-running staging ring:
//  - job0's t=14/15 stage job1's tiles 0/1 into the slots being freed ->
//    job1 starts with a FULL pipeline (zero fill cost);
//  - job0's epilogue burst (HBM) executes while job1's tiles fly (hidden).
// Gates: uniform counted GATE(3) (3 loads/thread/tile); seam is safe by
// FIFO order (stages are older than epilogue loads/atomics). Final job tail:
// GATE(3) at t=14, GATE(0) at t=15. All components verified in R18/R21:
// packed conflict-free layout, identity staging, fp8 math, epilogue.
__global__ __launch_bounds__(256)
void gemm_dot(const unsigned char* __restrict__ c8p, const unsigned char* __restrict__ wtp,
              const float* __restrict__ Ais, const float* __restrict__ Aem,
              float* __restrict__ delta) {
    __shared__ char smem[36864];   // slot s at s*12288: A 8 KiB | B 4 KiB

    const int tid  = threadIdx.x;
    const int lane = tid & 63;
    const int lr   = lane & 15;
    const int hi   = lane >> 4;
    const int wave = tid >> 6;
    const int wr   = wave >> 1;          // 64-row half
    const int wc   = wave & 1;           // 32-col half

    // 1024 jobs = 8 xcd x (8 panels x 16 colb). Block b owns jobs
    // local=q and local=q+64 of its xcd (q = b>>3, 0..63).
    const int bid = blockIdx.x;
    const int xcd = bid & 7;
    const int q   = bid >> 3;

    auto jobRB = [&](int local) { return (xcd * 8 + (local >> 4)) * 128; };
    auto jobCB = [&](int local) { return (local & 15) * 64; };

    // stage one K-step of job (ap0,bp0): A 4 units + B 2 units, 3 loads/thread
    auto stage = [&](int slot, int t, int ap0, int bp0) {
#pragma unroll
        for (int j = 0; j < 2; ++j) {
            const int off = j * 4096 + tid * 16;
            const int u   = off >> 11;
            const int w   = off & 2047;
            const size_t gA = ((size_t)(ap0 + (u >> 1)) * 32 + (2 * t + (u & 1))) * 2048 + w;
            gload_lds16(c8p + gA, smem + slot * 12288 + off);
        }
        {
            const int off2 = tid * 16;
            const int u2   = off2 >> 11;
            const int w2   = off2 & 2047;
            const size_t gB = ((size_t)bp0 * 32 + (2 * t + u2)) * 2048 + w2;
            gload_lds16(wtp + gB, smem + slot * 12288 + 8192 + off2);
        }
    };

    int s0 = 0, s1 = 1, s2 = 2;

    // prologue: job0 tiles 0,1
    {
        const int rb0 = jobRB(q), cb0 = jobCB(q);
        stage(0, 0, rb0 >> 6, cb0 >> 6);
        stage(1, 1, rb0 >> 6, cb0 >> 6);
    }

    for (int job = 0; job < 2; ++job) {
        const int local = q + job * 64;
        const int rb = jobRB(local), cb = jobCB(local);
        const int ap0 = rb >> 6, bp0 = cb >> 6;
        const int nlocal = q + 64;                 // next job (job==0 only)
        const int nap0 = jobRB(nlocal) >> 6, nbp0 = jobCB(nlocal) >> 6;

        f32x4 acc[4][2] = {};

        for (int t = 0; t < NSTEPS; ++t) {
            if (job == 1 && t == NSTEPS - 1) GATE(0); else GATE(3);
            RBAR();

            // frag reads: lane-linear, conflict-free
            const char* Ab = smem + s0 * 12288;
            const char* Bb = Ab + 8192;
            long a[4][2], b[2][2];
#pragma unroll
            for (int kk = 0; kk < 2; ++kk) {
                const int au = (wr * 2 + kk) * 2048 + lane * 8;
                const int bu = kk * 2048 + wc * 1024 + lane * 8;
#pragma unroll
                for (int mi = 0; mi < 4; ++mi) a[mi][kk] = *(const long*)(Ab + au + mi * 512);
#pragma unroll
                for (int ni = 0; ni < 2; ++ni) b[ni][kk] = *(const long*)(Bb + bu + ni * 512);
            }
            LGKM0();

            // continuous ring: this job's t+2, or (job0 only) next job's 0/1
            if (t + 2 < NSTEPS)       stage(s2, t + 2, ap0, bp0);
            else if (job == 0)        stage(s2, t + 2 - NSTEPS, nap0, nbp0);

            __builtin_amdgcn_s_setprio(1);
#pragma unroll
            for (int kk = 0; kk < 2; ++kk)
#pragma unroll
                for (int mi = 0; mi < 4; ++mi)
#pragma unroll
                    for (int ni = 0; ni < 2; ++ni)
                        acc[mi][ni] = __builtin_amdgcn_mfma_f32_16x16x32_fp8_fp8(
                            a[mi][kk], b[ni][kk], acc[mi][ni], 0, 0, 0);
            __builtin_amdgcn_s_setprio(0);

            int tmp = s0; s0 = s1; s1 = s2; s2 = tmp;
        }

        // epilogue for this job (R21-verified form); for job0 it runs while
        // job1's tiles 0/1 are in flight (issued above) -> burst hidden.
        const int colbase = cb + wc * 32 + lr;
        const int rowbase = rb + wr * 64 + hi * 4;
#pragma unroll
        for (int mi = 0; mi < 4; ++mi) {
#pragma unroll
            for (int jj = 0; jj < 4; ++jj) {
                const int r = rowbase + mi * 16 + jj;
                float v = 0.f;
#pragma unroll
                for (int ni = 0; ni < 2; ++ni) {
                    const size_t idx = (size_t)r * E_DIM + colbase + ni * 16;
                    v += acc[mi][ni][jj] * (Ais[idx] - Aem[idx]);
                }
                v += __shfl_xor(v, 1);
                v += __shfl_xor(v, 2);
                v += __shfl_xor(v, 4);
                v += __shfl_xor(v, 8);
                if (lr == 0) atomicAdd(&delta[r], v * (1.0f / WSCALE));
            }
        }
    }
}

__global__ void hinge_sum(const float* __restrict__ delta, float* __restrict__ out) {
    float s = 0.f;
    for (int i = threadIdx.x; i < B_ROWS; i += 256)
        s += fmaxf(MARGIN + delta[i], 0.f);
#pragma unroll
    for (int off = 32; off > 0; off >>= 1) s += __shfl_down(s, off);
    __shared__ float wsum[4];
    int lane = threadIdx.x & 63, w = threadIdx.x >> 6;
    if (lane == 0) wsum[w] = s;
    __syncthreads();
    if (threadIdx.x == 0) out[0] = wsum[0] + wsum[1] + wsum[2] + wsum[3];
}

extern "C" void kernel_launch(void* const* d_in, const int* in_sizes, int n_in,
                              void* d_out, int out_size, void* d_ws, size_t ws_size,
                              hipStream_t stream) {
    const float* A_is = (const float*)d_in[0];
    const float* A_em = (const float*)d_in[1];
    const float* m    = (const float*)d_in[2];
    const float* tr_m = (const float*)d_in[3];
    const float* W    = (const float*)d_in[4];
    // d_in[5] = b : cancels in diag_is - diag_em, unused.
    float* out = (float*)d_out;

    char* ws = (char*)d_ws;
    unsigned char* c8p = (unsigned char*)ws;                             // 8 MiB
    unsigned char* wtp = (unsigned char*)(ws + (size_t)8 * 1024 * 1024); // 1 MiB
    float*         delta = (float*)(ws + (size_t)9 * 1024 * 1024);       // 32 KiB

    prep_combo<<<4640, 256, 0, stream>>>(m, tr_m, c8p, W, wtp, delta);
    gemm_dot<<<512, 256, 0, stream>>>(c8p, wtp, A_is, A_em, delta);
    hinge_sum<<<1, 256, 0, stream>>>(delta, out);
}

// Round 23
// 49.687 us; speedup vs baseline: 1.1458x; 1.1458x over previous
//
#include <hip/hip_runtime.h>
#include <hip/hip_bf16.h>
#include <hip/hip_fp8.h>

#define B_ROWS 8192
#define E_DIM  1024
#define MARGIN 0.2f
#define BK 64                 // fp8 elements per K-step (2 ktiles of 32)
#define NSTEPS (E_DIM / BK)   // 16
#define WSCALE 16.0f          // W scaled into e4m3 sweet spot; undone in epilogue

typedef float f32x4 __attribute__((ext_vector_type(4)));

__device__ __forceinline__ void gload_lds16(const void* g, void* l) {
    __builtin_amdgcn_global_load_lds(
        (__attribute__((address_space(1))) void*)(g),
        (__attribute__((address_space(3))) void*)(l),
        16, 0, 0);
}

#define GATE(N) do { asm volatile("s_waitcnt vmcnt(" #N ")" ::: "memory"); \
                     __builtin_amdgcn_sched_barrier(0); } while (0)
#define RBAR()  do { __builtin_amdgcn_s_barrier(); \
                     __builtin_amdgcn_sched_barrier(0); } while (0)
#define LGKM0() do { asm volatile("s_waitcnt lgkmcnt(0)" ::: "memory"); \
                     __builtin_amdgcn_sched_barrier(0); } while (0)

__device__ __forceinline__ unsigned char to_fp8(float x) {
    return __hip_fp8_e4m3(x).__x;
}

// Fragment-packed layouts (unit = [panel64][ktile32], 2 KiB each):
//   unit byte (mi*512 + lane*8 + j) = value[row = panel*64 + mi*16 + (lane&15)]
//                                          [k   = ktile*32 + (lane>>4)*8 + j]
// c8p: 128 panels x 32 ktiles (8 MiB). wtp: 16 panels x 32 ktiles (1 MiB),
// value = 16*W[k][n] (transposed on the fly).
// blocks [0,4096): c-pack; [4096,4608): W-pack; [4608,4640): zero delta.
__global__ __launch_bounds__(256)
void prep_combo(const float* __restrict__ m, const float* __restrict__ trm,
                unsigned char* __restrict__ c8p,
                const float* __restrict__ W, unsigned char* __restrict__ wtp,
                float* __restrict__ delta) {
    const int tid = threadIdx.x;
    const int mi  = tid >> 6;
    const int l   = tid & 63;
    const int lr  = l & 15;
    const int hi  = l >> 4;
    if (blockIdx.x < 4096) {
        const int unit  = blockIdx.x;
        const int panel = unit >> 5;
        const int kt    = unit & 31;
        const size_t g  = (size_t)(panel * 64 + mi * 16 + lr) * E_DIM + kt * 32 + hi * 8;
        float4 m0 = *(const float4*)(m + g);
        float4 m1 = *(const float4*)(m + g + 4);
        float4 t0 = *(const float4*)(trm + g);
        float4 t1 = *(const float4*)(trm + g + 4);
        union { unsigned char b[8]; unsigned long long u; } r;
        r.b[0] = to_fp8(0.4f*m0.x + 0.6f*t0.x);
        r.b[1] = to_fp8(0.4f*m0.y + 0.6f*t0.y);
        r.b[2] = to_fp8(0.4f*m0.z + 0.6f*t0.z);
        r.b[3] = to_fp8(0.4f*m0.w + 0.6f*t0.w);
        r.b[4] = to_fp8(0.4f*m1.x + 0.6f*t1.x);
        r.b[5] = to_fp8(0.4f*m1.y + 0.6f*t1.y);
        r.b[6] = to_fp8(0.4f*m1.z + 0.6f*t1.z);
        r.b[7] = to_fp8(0.4f*m1.w + 0.6f*t1.w);
        *(unsigned long long*)(c8p + (size_t)unit * 2048 + mi * 512 + l * 8) = r.u;
    } else if (blockIdx.x < 4608) {
        const int unit = blockIdx.x - 4096;
        const int np   = unit >> 5;
        const int kt   = unit & 31;
        const int n    = np * 64 + mi * 16 + lr;
        const int k0   = kt * 32 + hi * 8;
        union { unsigned char b[8]; unsigned long long u; } r;
#pragma unroll
        for (int j = 0; j < 8; ++j)
            r.b[j] = to_fp8(W[(size_t)(k0 + j) * E_DIM + n] * WSCALE);
        *(unsigned long long*)(wtp + (size_t)unit * 2048 + mi * 512 + l * 8) = r.u;
    } else {
        delta[(blockIdx.x - 4608) * 256 + threadIdx.x] = 0.f;
    }
}

// BEST-VERIFIED GEMM (R21) + stage-early tweak: tile 128x64, grid 1024
// (64 panels x 16 colb -- no dA duplication), LDS 36 KiB -> 4 blocks/CU.
// Packed conflict-free layout (R18: 0 bank conflicts), identity staging,
// ring-of-3 + counted GATE(3) + one raw barrier/K-step, fp8 math verified
// (R17/R18/R21). stage(t+2) issues immediately after RBAR (slot provably
// free: all waves passed iter t-1's LGKM0 before this barrier) -> longer
// load flight. 4 waves each own 64x32 output (acc[4][2]).
__global__ __launch_bounds__(256)
void gemm_dot(const unsigned char* __restrict__ c8p, const unsigned char* __restrict__ wtp,
              const float* __restrict__ Ais, const float* __restrict__ Aem,
              float* __restrict__ delta) {
    __shared__ char smem[36864];   // slot s at s*12288: A 8 KiB | B 4 KiB

    const int tid  = threadIdx.x;
    const int lane = tid & 63;
    const int lr   = lane & 15;
    const int hi   = lane >> 4;
    const int wave = tid >> 6;
    const int wr   = wave >> 1;          // 0..1 : 64-row half
    const int wc   = wave & 1;           // 0..1 : 32-col half

    // XCD swizzle: xcd owns 8 row-panels x 16 colb; per-XCD reuse set =
    // 8 c8-panels (1 MiB) + wtp (1 MiB) ~ L2-resident.
    const int bid = blockIdx.x;
    const int xcd = bid & 7;
    const int q   = bid >> 3;            // 0..127
    const int rb  = (xcd * 8 + (q >> 4)) * 128;
    const int cb  = (q & 15) * 64;
    const int ap0 = rb >> 6;             // first A panel (of 2)
    const int bp0 = cb >> 6;             // B panel (1)

    // stage one K-step (12 KiB: A 4 units + B 2 units), identity copy;
    // 3 gload_lds per thread.
    auto stage = [&](int slot, int t) {
#pragma unroll
        for (int j = 0; j < 2; ++j) {
            const int off = j * 4096 + tid * 16;   // 0..8191 (A region)
            const int u   = off >> 11;             // 0..3
            const int w   = off & 2047;
            const size_t gA = ((size_t)(ap0 + (u >> 1)) * 32 + (2 * t + (u & 1))) * 2048 + w;
            gload_lds16(c8p + gA, smem + slot * 12288 + off);
        }
        {
            const int off2 = tid * 16;             // 0..4095 (B region)
            const int u2   = off2 >> 11;           // 0..1
            const int w2   = off2 & 2047;
            const size_t gB = ((size_t)bp0 * 32 + (2 * t + u2)) * 2048 + w2;
            gload_lds16(wtp + gB, smem + slot * 12288 + 8192 + off2);
        }
    };

    f32x4 acc[4][2] = {};

    stage(0, 0);
    stage(1, 1);

    int s0 = 0, s1 = 1, s2 = 2;
    for (int t = 0; t < NSTEPS; ++t) {
        if (t + 1 < NSTEPS) GATE(3); else GATE(0);   // certify tile t
        RBAR();

        // stage tile t+2 FIRST (slot s2 provably free after the barrier):
        // loads get the frag-read + MFMA phases of flight before next gate
        if (t + 2 < NSTEPS) stage(s2, t + 2);

        // frag reads: lane-linear (base + lane*8), conflict-free
        const char* Ab = smem + s0 * 12288;
        const char* Bb = Ab + 8192;
        long a[4][2], b[2][2];
#pragma unroll
        for (int kk = 0; kk < 2; ++kk) {
            const int au = (wr * 2 + kk) * 2048 + lane * 8;   // A panel wr, ktile kk
            const int bu = kk * 2048 + wc * 1024 + lane * 8;  // B ktile kk, col-half wc
#pragma unroll
            for (int mi = 0; mi < 4; ++mi) a[mi][kk] = *(const long*)(Ab + au + mi * 512);
#pragma unroll
            for (int ni = 0; ni < 2; ++ni) b[ni][kk] = *(const long*)(Bb + bu + ni * 512);
        }
        LGKM0();

        __builtin_amdgcn_s_setprio(1);
#pragma unroll
        for (int kk = 0; kk < 2; ++kk)
#pragma unroll
            for (int mi = 0; mi < 4; ++mi)
#pragma unroll
                for (int ni = 0; ni < 2; ++ni)
                    acc[mi][ni] = __builtin_amdgcn_mfma_f32_16x16x32_fp8_fp8(
                        a[mi][kk], b[ni][kk], acc[mi][ni], 0, 0, 0);
        __builtin_amdgcn_s_setprio(0);

        int tmp = s0; s0 = s1; s1 = s2; s2 = tmp;
    }

    // epilogue (R15/R18/R21-verified form): delta[r] += (1/WSCALE)*sum u*dA
    // C/D layout (16x16x32): col = lane&15, row = (lane>>4)*4 + reg
    const int colbase = cb + wc * 32 + lr;
    const int rowbase = rb + wr * 64 + hi * 4;
#pragma unroll
    for (int mi = 0; mi < 4; ++mi) {
#pragma unroll
        for (int jj = 0; jj < 4; ++jj) {
            const int r = rowbase + mi * 16 + jj;
            float v = 0.f;
#pragma unroll
            for (int ni = 0; ni < 2; ++ni) {
                const size_t idx = (size_t)r * E_DIM + colbase + ni * 16;
                v += acc[mi][ni][jj] * (Ais[idx] - Aem[idx]);
            }
            v += __shfl_xor(v, 1);
            v += __shfl_xor(v, 2);
            v += __shfl_xor(v, 4);
            v += __shfl_xor(v, 8);
            if (lr == 0) atomicAdd(&delta[r], v * (1.0f / WSCALE));
        }
    }
}

__global__ void hinge_sum(const float* __restrict__ delta, float* __restrict__ out) {
    float s = 0.f;
    for (int i = threadIdx.x; i < B_ROWS; i += 256)
        s += fmaxf(MARGIN + delta[i], 0.f);
#pragma unroll
    for (int off = 32; off > 0; off >>= 1) s += __shfl_down(s, off);
    __shared__ float wsum[4];
    int lane = threadIdx.x & 63, w = threadIdx.x >> 6;
    if (lane == 0) wsum[w] = s;
    __syncthreads();
    if (threadIdx.x == 0) out[0] = wsum[0] + wsum[1] + wsum[2] + wsum[3];
}

extern "C" void kernel_launch(void* const* d_in, const int* in_sizes, int n_in,
                              void* d_out, int out_size, void* d_ws, size_t ws_size,
                              hipStream_t stream) {
    const float* A_is = (const float*)d_in[0];
    const float* A_em = (const float*)d_in[1];
    const float* m    = (const float*)d_in[2];
    const float* tr_m = (const float*)d_in[3];
    const float* W    = (const float*)d_in[4];
    // d_in[5] = b : cancels in diag_is - diag_em, unused.
    float* out = (float*)d_out;

    char* ws = (char*)d_ws;
    unsigned char* c8p = (unsigned char*)ws;                             // 8 MiB
    unsigned char* wtp = (unsigned char*)(ws + (size_t)8 * 1024 * 1024); // 1 MiB
    float*         delta = (float*)(ws + (size_t)9 * 1024 * 1024);       // 32 KiB

    prep_combo<<<4640, 256, 0, stream>>>(m, tr_m, c8p, W, wtp, delta);
    gemm_dot<<<1024, 256, 0, stream>>>(c8p, wtp, A_is, A_em, delta);
    hinge_sum<<<1, 256, 0, stream>>>(delta, out);
}